// Round 13
// baseline (271.619 us; speedup 1.0000x reference)
//
#include <hip/hip_runtime.h>

#define NN 20000
#define CPAD 41

typedef _Float16 f16x2 __attribute__((ext_vector_type(2)));
typedef unsigned short u16x2 __attribute__((ext_vector_type(2)));

union U32H2 { unsigned int u; f16x2 h; };
union U32S2 { unsigned int u; u16x2 s; };

__device__ __forceinline__ f16x2 bc_h2(unsigned int u) { U32H2 x; x.u = u; return x.h; }
__device__ __forceinline__ unsigned int dup_h(float v) {
    _Float16 h = (_Float16)v;
    unsigned short b = __builtin_bit_cast(unsigned short, h);
    return ((unsigned int)b << 16) | b;
}
__device__ __forceinline__ unsigned int pkrtz_u32(float a, float b) {
    return __builtin_bit_cast(unsigned int, __builtin_amdgcn_cvt_pkrtz(a, b));
}
// spread u8-pair (lo byte, hi byte) into u16x2 lanes: [b_lo, 0, b_hi, 0]
__device__ __forceinline__ unsigned int spread8(unsigned int g) {
    return __builtin_amdgcn_perm(0u, g, 0x0C010C00u);  // v_perm_b32
}

template <int CTRL>
__device__ __forceinline__ unsigned int pkmax_dpp(unsigned int v) {
    unsigned int d = (unsigned int)__builtin_amdgcn_update_dpp(
        0, (int)v, CTRL, 0xF, 0xF, true);
    U32S2 a, b; a.u = v; b.u = d;
    a.s = __builtin_elementwise_max(a.s, b.s);
    return a.u;
}
__device__ __forceinline__ unsigned int octmax_u16x2(unsigned int v) {
    v = pkmax_dpp<0xB1>(v);    // quad_perm xor1
    v = pkmax_dpp<0x4E>(v);    // quad_perm xor2
    v = pkmax_dpp<0x141>(v);   // row_half_mirror (xor4 within 8)
    return v;
}

// ---------------- prep: softmax(W) -> packed-f16 pi tables ----------------
__global__ __launch_bounds__(1024) void prep_kernel(const float* __restrict__ W,
                                                    unsigned int* __restrict__ pi_pk,
                                                    unsigned int* __restrict__ pi_t_pk,
                                                    unsigned int* __restrict__ pi1_pk,
                                                    unsigned int* __restrict__ pi2_pk) {
    __shared__ float red[1024];
    __shared__ float piL[4096];
    int t = threadIdx.x;
    float4 wv = ((const float4*)W)[t];
    float m = fmaxf(fmaxf(wv.x, wv.y), fmaxf(wv.z, wv.w));
    red[t] = m; __syncthreads();
    for (int s = 512; s > 0; s >>= 1) {
        if (t < s) red[t] = fmaxf(red[t], red[t + s]);
        __syncthreads();
    }
    m = red[0];
    __syncthreads();
    float e0 = expf(wv.x - m), e1 = expf(wv.y - m);
    float e2 = expf(wv.z - m), e3 = expf(wv.w - m);
    red[t] = e0 + e1 + e2 + e3;
    __syncthreads();
    for (int s = 512; s > 0; s >>= 1) {
        if (t < s) red[t] += red[t + s];
        __syncthreads();
    }
    float inv = 1.0f / red[0];
    float p[4] = { e0 * inv, e1 * inv, e2 * inv, e3 * inv };
#pragma unroll
    for (int i = 0; i < 4; i++) {
        int f = t * 4 + i;
        piL[f] = p[i];
        unsigned int d = dup_h(p[i]);
        pi_pk[f] = d;
        pi_t_pk[(f & 63) * 64 + (f >> 6)] = d;  // transposed [k][j]
    }
    __syncthreads();
    if (t < 64) {
        float s = 0.f;
        for (int k = 0; k < 64; k++) s += piL[t * 64 + k];
        pi1_pk[t] = dup_h(s);
    } else if (t < 128) {
        int k = t - 64;
        float s = 0.f;
        for (int j = 0; j < 64; j++) s += piL[j * 64 + k];
        pi2_pk[k] = dup_h(s);
    }
}

// ---------------- pack a0 fp32 (B,N) planes -> two u8x2 tables ----------------
__global__ __launch_bounds__(1024) void pack_kernel(const float* __restrict__ a0,
                                                    unsigned short* __restrict__ T0) {
    int i = blockIdx.x * 1024 + threadIdx.x;
    if (i < NN) {
        unsigned int b0 = __float2uint_rn(__saturatef(a0[i]) * 255.0f);
        unsigned int b1 = __float2uint_rn(__saturatef(a0[NN + i]) * 255.0f);
        unsigned int b2 = __float2uint_rn(__saturatef(a0[2 * NN + i]) * 255.0f);
        unsigned int b3 = __float2uint_rn(__saturatef(a0[3 * NN + i]) * 255.0f);
        T0[i] = (unsigned short)(b0 | (b1 << 8));        // bpair 0
        T0[NN + i] = (unsigned short)(b2 | (b3 << 8));   // bpair 1
    }
}

// ---------------- phase 1: clause gathers (R11 lane map, 1 chain) ----------------
__device__ __forceinline__ void phase1(
    const unsigned short* __restrict__ tab,
    unsigned int (* __restrict__ Ftb)[CPAD],
    const int* __restrict__ X1, const int* __restrict__ X2,
    int nb, int cn, int widu, int ni, int w) {
    const float sc = 1.0f / 65025.0f;
    int loff[5];
#pragma unroll
    for (int oc = 0; oc < 5; ++oc) {
        int n = nb + oc * 8 + ni;
        int nc = n < NN ? n : NN - 1;
        loff[oc] = nc * 64 + w * 8;
    }
    int2 qb[2][5];
#pragma unroll
    for (int d = 0; d < 2; ++d) {
        const int row = widu + 16 * d, k = row & 63;
        const char* Xb = (const char*)((row >> 6) ? X2 : X1) + (unsigned)(k * NN) * 64u;
#pragma unroll
        for (int oc = 0; oc < 5; ++oc) qb[d][oc] = *(const int2*)(Xb + loff[oc]);
    }
#pragma unroll
    for (int rr = 0; rr < 8; ++rr) {
        const int cur = rr & 1;
        unsigned int ga[5], gb[5];
#pragma unroll
        for (int oc = 0; oc < 5; ++oc) {
            ga[oc] = tab[qb[cur][oc].x];
            gb[oc] = tab[qb[cur][oc].y];
        }
        if (rr < 6) {
            const int row2 = widu + 16 * (rr + 2), k2 = row2 & 63;
            const char* Xb = (const char*)((row2 >> 6) ? X2 : X1)
                           + (unsigned)(k2 * NN) * 64u;
#pragma unroll
            for (int oc = 0; oc < 5; ++oc) qb[cur][oc] = *(const int2*)(Xb + loff[oc]);
        }
        const int row = widu + 16 * rr;
#pragma unroll
        for (int oc = 0; oc < 5; ++oc) {
            U32S2 a, b;
            a.u = spread8(ga[oc]);
            b.u = spread8(gb[oc]);
            a.s = a.s * b.s;                       // one packed-u16 product
            unsigned int peu = octmax_u16x2(a.u);  // 3 DPP chain
            int col = oc * 8 + ni;
            if (w == 0 && col < cn) {
                float f0 = (float)(peu & 0xFFFFu) * sc;
                float f1 = (float)(peu >> 16) * sc;
                Ftb[row][col] = pkrtz_u32(f0, f1);
            }
        }
    }
}

// ---------------- phase 2: bilinear partials for (gu, n_l) ----------------
__device__ __forceinline__ float2 phase2(
    const unsigned int (* __restrict__ Ftb)[CPAD],
    const unsigned int* __restrict__ pi_t_pk,
    const unsigned int* __restrict__ pi1_pk,
    const unsigned int* __restrict__ pi2_pk,
    int gu, int n_l) {
    f16x2 zero = {(_Float16)0, (_Float16)0};
    f16x2 f1v[4];
    f16x2 eu = zero;
#pragma unroll
    for (int ji = 0; ji < 4; ++ji) {
        f1v[ji] = bc_h2(Ftb[gu * 4 + ji][n_l]);
        eu += bc_h2(pi1_pk[gu * 4 + ji]) * f1v[ji];  // s_load
    }
    f16x2 euv = zero, ev = zero;
#pragma unroll 8
    for (int k = 0; k < 64; ++k) {
        f16x2 f2 = bc_h2(Ftb[64 + k][n_l]);
        uint4 wv = *(const uint4*)(pi_t_pk + k * 64 + gu * 4);  // s_load_dwordx4
        f16x2 ts = bc_h2(wv.x) * f1v[0] + bc_h2(wv.y) * f1v[1] +
                   bc_h2(wv.z) * f1v[2] + bc_h2(wv.w) * f1v[3];
        euv += f2 * ts;
        if (gu == 0) ev += bc_h2(pi2_pk[k]) * f2;
    }
    float p0 = (float)eu[0] - (float)euv[0];
    float p1 = (float)eu[1] - (float)euv[1];
    if (gu == 0) { p0 += (float)ev[0]; p1 += (float)ev[1]; }
    return make_float2(p0, p1);
}

// ---------------- fused iteration, batch-pair split (2 blocks/CU) ----------------
// blockIdx.x = bpair p (0: b0b1, 1: b2b3), blockIdx.y = n-range.
// LDS = 40,000 (tab u8x2) + 20,992 (Ft) + 8,192 (redp) = 69,184 B -> 2 blocks/CU,
// 8 waves/SIMD (the latency-cover R9-R12 lacked).
template <int ITER>
__global__ __launch_bounds__(1024, 8) void fused_iter(
    const unsigned short* __restrict__ Tsrc,   // base of both bpair tables
    const int* __restrict__ X1, const int* __restrict__ X2,
    const unsigned int* __restrict__ pi_t_pk,
    const unsigned int* __restrict__ pi1_pk,
    const unsigned int* __restrict__ pi2_pk,
    const float* __restrict__ a0,
    unsigned short* __restrict__ Tdst, float* __restrict__ outP) {
    __shared__ unsigned short tab[NN];        // 40,000 B
    __shared__ unsigned int Ft[128][CPAD];    // 20,992 B
    __shared__ float redp[16][64][2];         //  8,192 B

    const int t = threadIdx.x;
    const int p = (int)blockIdx.x;
    const unsigned short* Tp = Tsrc + p * NN;
    for (int i = t; i < NN; i += 1024) tab[i] = Tp[i];

    const int bid = (int)blockIdx.y;
    const int bstart = bid < 32 ? bid * 79 : 32 * 79 + (bid - 32) * 78;
    const int bcnt = bid < 32 ? 79 : 78;
    const int c0 = (bcnt + 1) >> 1;  // 40 or 39

    const int wid = t >> 6, lane = t & 63, ni = lane >> 3, w = lane & 7;
    const int g = t >> 6, n_l = t & 63;
    const int widu = __builtin_amdgcn_readfirstlane(wid);
    const int gu = widu;  // same wave-uniform value

    __syncthreads();  // tab ready

    for (int ch = 0; ch < 2; ++ch) {
        const int nb = bstart + (ch ? c0 : 0);
        const int cn = ch ? (bcnt - c0) : c0;

        phase1(tab, Ft, X1, X2, nb, cn, widu, ni, w);
        __syncthreads();

        if (n_l < cn) {
            float2 pp = phase2(Ft, pi_t_pk, pi1_pk, pi2_pk, gu, n_l);
            *(float2*)&redp[g][n_l][0] = pp;
        }
        __syncthreads();

        if (t < cn) {
            int gn = nb + t;
            float d0 = 0.f, d1 = 0.f;
#pragma unroll
            for (int g16 = 0; g16 < 16; ++g16) {
                d0 += redp[g16][t][0];
                d1 += redp[g16][t][1];
            }
            float ap0, ap1;
            if (ITER == 1) {
                ap0 = a0[(size_t)(2 * p) * NN + gn];
                ap1 = a0[(size_t)(2 * p + 1) * NN + gn];
            } else {
                unsigned int tv = tab[gn];
                ap0 = (float)(tv & 255u) * (1.0f / 255.0f);
                ap1 = (float)(tv >> 8) * (1.0f / 255.0f);
            }
            float an0 = 1.0f - (1.0f - ap0) * (1.0f - d0);
            float an1 = 1.0f - (1.0f - ap1) * (1.0f - d1);
            if (ITER == 1) {
                unsigned int b0 = __float2uint_rn(__saturatef(an0) * 255.0f);
                unsigned int b1 = __float2uint_rn(__saturatef(an1) * 255.0f);
                Tdst[p * NN + gn] = (unsigned short)(b0 | (b1 << 8));
            } else {
                outP[(size_t)(2 * p) * NN + gn] = an0;
                outP[(size_t)(2 * p + 1) * NN + gn] = an1;
            }
        }
    }
}

extern "C" void kernel_launch(void* const* d_in, const int* in_sizes, int n_in,
                              void* d_out, int out_size, void* d_ws, size_t ws_size,
                              hipStream_t stream) {
    const float* a0 = (const float*)d_in[0];
    const float* W = (const float*)d_in[1];
    const int* X1 = (const int*)d_in[2];   // int64 in ref -> int32 on device
    const int* X2 = (const int*)d_in[3];
    float* out = (float*)d_out;

    // ws: pi_pk @0 (16,384) | pi_t @16,384 (16,384) | pi1 @32,768 (256)
    // | pi2 @33,024 (256) | T0 @33,280 (80,000: 2 u8x2 planes) | T1 @113,280
    if (ws_size < (size_t)193280) return;  // R5 measured ws >= 20.8 MB
    unsigned int* pi_pk  = (unsigned int*)d_ws;
    unsigned int* pi_t   = (unsigned int*)((char*)d_ws + 16384);
    unsigned int* pi1_pk = (unsigned int*)((char*)d_ws + 32768);
    unsigned int* pi2_pk = (unsigned int*)((char*)d_ws + 33024);
    unsigned short* T0   = (unsigned short*)((char*)d_ws + 33280);
    unsigned short* T1   = (unsigned short*)((char*)d_ws + 113280);

    prep_kernel<<<1, 1024, 0, stream>>>(W, pi_pk, pi_t, pi1_pk, pi2_pk);
    pack_kernel<<<20, 1024, 0, stream>>>(a0, T0);
    fused_iter<1><<<dim3(2, 256), 1024, 0, stream>>>(T0, X1, X2, pi_t, pi1_pk,
                                                     pi2_pk, a0, T1, nullptr);
    fused_iter<2><<<dim3(2, 256), 1024, 0, stream>>>(T1, X1, X2, pi_t, pi1_pk,
                                                     pi2_pk, nullptr, nullptr, out);
}